// Round 11
// baseline (737.434 us; speedup 1.0000x reference)
//
#include <hip/hip_runtime.h>
#include <hip/hip_bf16.h>
#include <stdint.h>

#define B_ 4
#define S_IN 32768
#define C1V 128
#define L1V 16384
#define C2V 256
#define L2V 8192
#define C3V 512
#define L3V 4096
#define VOCABV 2048
#define KCB 4

// padded hi/lo f16 plane layout for conv activations:
// row r = b*C + c, row stride R = 2*(L+16) halfs; hi plane at [8 .. L+8), lo at +P=(L+16).
#define R1P (2 * (L1V + 16))
#define P1P (L1V + 16)
#define R2P (2 * (L2V + 16))
#define P2P (L2V + 16)

typedef _Float16 half8 __attribute__((ext_vector_type(8)));
typedef float floatx4 __attribute__((ext_vector_type(4)));
typedef float floatx16 __attribute__((ext_vector_type(16)));

#define AS1 __attribute__((address_space(1)))
#define AS3 __attribute__((address_space(3)))

__device__ __forceinline__ void gload_lds16(const void* g, void* l) {
    __builtin_amdgcn_global_load_lds((const AS1 void*)g, (AS3 void*)l, 16, 0, 0);
}

// read 8 halfs at a 4B-aligned LDS address (4x ds_read_b32)
__device__ __forceinline__ half8 lds_read_half8_a4(const _Float16* p) {
    union { uint32_t u[4]; half8 h; } t;
    const uint32_t* w = (const uint32_t*)p;
    t.u[0] = w[0]; t.u[1] = w[1]; t.u[2] = w[2]; t.u[3] = w[3];
    return t.h;
}

// ---------------- pad zeroing for x1/x2 hi-lo buffers (runs first) ----------------
__global__ void padzero_kernel(_Float16* __restrict__ x1h, _Float16* __restrict__ x2h) {
    int j = blockIdx.x * 256 + threadIdx.x;
    half8 z;
#pragma unroll
    for (int i = 0; i < 8; ++i) z[i] = (_Float16)0.f;
    if (j < 2048) {
        int row = j >> 2, p = j & 3;
        size_t base = (size_t)row * R1P + (size_t)(p >> 1) * P1P + ((p & 1) ? (L1V + 8) : 0);
        *(half8*)(x1h + base) = z;
    } else if (j < 6144) {
        int j2 = j - 2048;
        int row = j2 >> 2, p = j2 & 3;
        size_t base = (size_t)row * R2P + (size_t)(p >> 1) * P2P + ((p & 1) ? (L2V + 8) : 0);
        *(half8*)(x2h + base) = z;
    }
}

// ---------------- conv1: [B,1,S] -> padded hi/lo f16 planes, k=7 s=2 p=3, relu -----
__global__ void conv1_kernel(const float* __restrict__ x, const float* __restrict__ w,
                             const float* __restrict__ bias, _Float16* __restrict__ out) {
    __shared__ float xs[2 * 256 + 6];
    __shared__ float ws[7];
    const int l0 = blockIdx.x * 256;
    const int co = blockIdx.y;
    const int b  = blockIdx.z;
    const int tid = threadIdx.x;
    const float* xb = x + (size_t)b * S_IN;
    for (int n = tid; n < 2 * 256 + 6; n += 256) {
        int p = 2 * l0 - 3 + n;
        xs[n] = (p >= 0 && p < S_IN) ? xb[p] : 0.f;
    }
    if (tid < 7) ws[tid] = w[co * 7 + tid];
    __syncthreads();
    float acc = bias[co];
    const int base = 2 * tid;
#pragma unroll
    for (int t = 0; t < 7; ++t) acc = fmaf(ws[t], xs[base + t], acc);
    float s = fmaxf(acc, 0.f) * 1024.f;
    _Float16 h  = (_Float16)s;
    _Float16 lo = (_Float16)(s - (float)h);
    size_t o = (size_t)(b * C1V + co) * R1P + 8 + l0 + tid;
    out[o] = h;
    out[o + P1P] = lo;
}

// ---------------- weight prep: w[co][ci][7] fp32 -> hi/lo f16 planes [co][ci*8+u] ----
__global__ void wsplit_kernel(const float* __restrict__ w, _Float16* __restrict__ wh,
                              _Float16* __restrict__ wl, int cin, int cout) {
    int idx = blockIdx.x * 256 + threadIdx.x;
    if (idx >= cin * cout) return;
    int co = idx / cin;
    int ci = idx - co * cin;
    const float* src = w + ((size_t)co * cin + ci) * 7;
    half8 h, l;
    h[0] = (_Float16)0.f; l[0] = (_Float16)0.f;
#pragma unroll
    for (int u = 1; u < 8; ++u) {
        float v = src[u - 1] * 1024.f;
        _Float16 hh = (_Float16)v;
        h[u] = hh;
        l[u] = (_Float16)(v - (float)hh);
    }
    size_t o = (size_t)co * (cin * 8) + ci * 8;
    *(half8*)(wh + o) = h;
    *(half8*)(wl + o) = l;
}

// ---------------- conv2 via f16 3-product MFMA: A=W (m=co), B=X windows (n=l) -------
__global__ __launch_bounds__(256, 2) void conv2_mfma_kernel(
    const _Float16* __restrict__ xin, const _Float16* __restrict__ WH,
    const _Float16* __restrict__ WL, const float* __restrict__ bias,
    _Float16* __restrict__ xout) {
    __shared__ _Float16 Xs[2176];
    __shared__ _Float16 WsH[128 * 32], WsL[128 * 32];
    const int tid = threadIdx.x;
    const int wave = tid >> 6;
    const int lane = tid & 63;
    const int wm = wave >> 1, wn = wave & 1;
    const int q  = lane >> 4;
    const int cl = lane & 15;
    const int l0  = blockIdx.x * 128;
    const int co0 = blockIdx.y * 128;
    const int b   = blockIdx.z;

    const int wrow  = lane >> 2;
    const int wseg  = lane & 3;
    const int wsoff = (wseg ^ ((wrow >> 1) & 3)) * 8;
    const int rq    = (q ^ ((cl >> 1) & 3)) * 8;

    const int pl0 = (tid >= 136) ? 1 : 0;
    const int r0  = tid - pl0 * 136;
    const int ci0 = r0 / 34;
    const int sg0 = r0 - ci0 * 34;
    const _Float16* xb = xin + (size_t)b * C1V * R1P;

    floatx4 acc[4][4];
#pragma unroll
    for (int a = 0; a < 4; ++a)
#pragma unroll
        for (int n = 0; n < 4; ++n) acc[a][n] = (floatx4){0.f, 0.f, 0.f, 0.f};

    for (int ch = 0; ch < 32; ++ch) {
        __syncthreads();
        {
            const _Float16* gx = xb + (size_t)(ch * 4 + ci0) * R1P + pl0 * P1P + 2 * l0 + sg0 * 8;
            gload_lds16(gx, (char*)Xs + (tid & ~63) * 16);
            if (tid < 16) {
                const _Float16* gt = xb + (size_t)(ch * 4 + 3) * R1P + P1P + 2 * l0 + (18 + tid) * 8;
                gload_lds16(gt, (char*)Xs + 4096);
            }
        }
        const int k0 = ch * 32;
        for (int g = wave; g < 8; g += 4) {
            const _Float16* gh = WH + (size_t)(co0 + g * 16 + wrow) * 1024 + k0 + wsoff;
            const _Float16* gl = WL + (size_t)(co0 + g * 16 + wrow) * 1024 + k0 + wsoff;
            gload_lds16(gh, (char*)WsH + g * 1024);
            gload_lds16(gl, (char*)WsL + g * 1024);
        }
        asm volatile("s_waitcnt vmcnt(0)" ::: "memory");
        __syncthreads();

        half8 awh[4], awl[4], bxh[4], bxl[4];
#pragma unroll
        for (int a = 0; a < 4; ++a) {
            const int ro = (wm * 64 + a * 16 + cl) * 32 + rq;
            awh[a] = *(const half8*)&WsH[ro];
            awl[a] = *(const half8*)&WsL[ro];
        }
#pragma unroll
        for (int n = 0; n < 4; ++n) {
            const int lrel = wn * 64 + n * 16 + cl;
            bxh[n] = lds_read_half8_a4(&Xs[q * 272 + 4 + 2 * lrel]);
            bxl[n] = lds_read_half8_a4(&Xs[1088 + q * 272 + 4 + 2 * lrel]);
        }
#pragma unroll
        for (int a = 0; a < 4; ++a)
#pragma unroll
            for (int n = 0; n < 4; ++n) {
                acc[a][n] = __builtin_amdgcn_mfma_f32_16x16x32_f16(awh[a], bxh[n], acc[a][n], 0, 0, 0);
                acc[a][n] = __builtin_amdgcn_mfma_f32_16x16x32_f16(awl[a], bxh[n], acc[a][n], 0, 0, 0);
                acc[a][n] = __builtin_amdgcn_mfma_f32_16x16x32_f16(awh[a], bxl[n], acc[a][n], 0, 0, 0);
            }
    }

    float bv[4][4];
#pragma unroll
    for (int a = 0; a < 4; ++a)
#pragma unroll
        for (int r = 0; r < 4; ++r) bv[a][r] = bias[co0 + wm * 64 + a * 16 + q * 4 + r];
#pragma unroll
    for (int a = 0; a < 4; ++a)
#pragma unroll
        for (int n = 0; n < 4; ++n) {
            const int l = l0 + wn * 64 + n * 16 + cl;
#pragma unroll
            for (int r = 0; r < 4; ++r) {
                const int co = co0 + wm * 64 + a * 16 + q * 4 + r;
                float vv = fmaxf(acc[a][n][r] * (1.f / 1048576.f) + bv[a][r], 0.f);
                float s = vv * 1024.f;
                _Float16 h  = (_Float16)s;
                _Float16 lo = (_Float16)(s - (float)h);
                size_t o = (size_t)(b * C2V + co) * R2P + 8 + l;
                xout[o] = h;
                xout[o + P2P] = lo;
            }
        }
}

// ---------------- conv3 via f16 3-product MFMA: A=X windows (m=l), B=W (n=co) -------
__global__ __launch_bounds__(256, 2) void conv3_mfma_kernel(
    const _Float16* __restrict__ xin, const _Float16* __restrict__ WH,
    const _Float16* __restrict__ WL, const float* __restrict__ bias,
    _Float16* __restrict__ outh) {
    __shared__ _Float16 Xs[2176];
    __shared__ _Float16 WsH[128 * 32], WsL[128 * 32];
    const int tid = threadIdx.x;
    const int wave = tid >> 6;
    const int lane = tid & 63;
    const int wm = wave >> 1, wn = wave & 1;
    const int q  = lane >> 4;
    const int cl = lane & 15;
    const int l0  = blockIdx.x * 128;
    const int co0 = blockIdx.y * 128;
    const int b   = blockIdx.z;

    const int wrow  = lane >> 2;
    const int wseg  = lane & 3;
    const int wsoff = (wseg ^ ((wrow >> 1) & 3)) * 8;
    const int rq    = (q ^ ((cl >> 1) & 3)) * 8;

    const int pl0 = (tid >= 136) ? 1 : 0;
    const int r0  = tid - pl0 * 136;
    const int ci0 = r0 / 34;
    const int sg0 = r0 - ci0 * 34;
    const _Float16* xb = xin + (size_t)b * C2V * R2P;

    floatx4 acc[4][4];
#pragma unroll
    for (int a = 0; a < 4; ++a)
#pragma unroll
        for (int n = 0; n < 4; ++n) acc[a][n] = (floatx4){0.f, 0.f, 0.f, 0.f};

    for (int ch = 0; ch < 64; ++ch) {
        __syncthreads();
        {
            const _Float16* gx = xb + (size_t)(ch * 4 + ci0) * R2P + pl0 * P2P + 2 * l0 + sg0 * 8;
            gload_lds16(gx, (char*)Xs + (tid & ~63) * 16);
            if (tid < 16) {
                const _Float16* gt = xb + (size_t)(ch * 4 + 3) * R2P + P2P + 2 * l0 + (18 + tid) * 8;
                gload_lds16(gt, (char*)Xs + 4096);
            }
        }
        const int k0 = ch * 32;
        for (int g = wave; g < 8; g += 4) {
            const _Float16* gh = WH + (size_t)(co0 + g * 16 + wrow) * 2048 + k0 + wsoff;
            const _Float16* gl = WL + (size_t)(co0 + g * 16 + wrow) * 2048 + k0 + wsoff;
            gload_lds16(gh, (char*)WsH + g * 1024);
            gload_lds16(gl, (char*)WsL + g * 1024);
        }
        asm volatile("s_waitcnt vmcnt(0)" ::: "memory");
        __syncthreads();

        half8 axh[4], axl[4], bwh[4], bwl[4];
#pragma unroll
        for (int a = 0; a < 4; ++a) {
            const int lrel = wm * 64 + a * 16 + cl;
            axh[a] = lds_read_half8_a4(&Xs[q * 272 + 4 + 2 * lrel]);
            axl[a] = lds_read_half8_a4(&Xs[1088 + q * 272 + 4 + 2 * lrel]);
        }
#pragma unroll
        for (int n = 0; n < 4; ++n) {
            const int ro = (wn * 64 + n * 16 + cl) * 32 + rq;
            bwh[n] = *(const half8*)&WsH[ro];
            bwl[n] = *(const half8*)&WsL[ro];
        }
#pragma unroll
        for (int a = 0; a < 4; ++a)
#pragma unroll
            for (int n = 0; n < 4; ++n) {
                acc[a][n] = __builtin_amdgcn_mfma_f32_16x16x32_f16(axh[a], bwh[n], acc[a][n], 0, 0, 0);
                acc[a][n] = __builtin_amdgcn_mfma_f32_16x16x32_f16(axl[a], bwh[n], acc[a][n], 0, 0, 0);
                acc[a][n] = __builtin_amdgcn_mfma_f32_16x16x32_f16(axh[a], bwl[n], acc[a][n], 0, 0, 0);
            }
    }

    float bv[4];
#pragma unroll
    for (int n = 0; n < 4; ++n) bv[n] = bias[co0 + wn * 64 + n * 16 + cl];
#pragma unroll
    for (int a = 0; a < 4; ++a)
#pragma unroll
        for (int n = 0; n < 4; ++n) {
            const int co = co0 + wn * 64 + n * 16 + cl;
#pragma unroll
            for (int r = 0; r < 4; ++r) {
                const int l = l0 + wm * 64 + a * 16 + q * 4 + r;
                float f = acc[a][n][r] * (1.f / 1048576.f) + bv[n];
                float s = f * 1024.f;
                _Float16 h = (_Float16)s;
                _Float16 lo = (_Float16)(s - (float)h);
                _Float16* dst = outh + ((size_t)b * L3V + l) * 1024 + co;
                dst[0] = h;
                dst[512] = lo;
            }
        }
}

// ---------------- fused codebook prep: rowsq*2^19 + x1024 hi/lo f16 split ----------
__global__ void cbprep_kernel(const float* __restrict__ cb, _Float16* __restrict__ y,
                              float* __restrict__ c2p) {
    const int r = blockIdx.x;
    const int lane = threadIdx.x;  // 64
    const float* row = cb + (size_t)r * 512;
    float4 a = *(const float4*)&row[lane * 8];
    float4 c = *(const float4*)&row[lane * 8 + 4];
    float s = a.x * a.x + a.y * a.y + a.z * a.z + a.w * a.w
            + c.x * c.x + c.y * c.y + c.z * c.z + c.w * c.w;
#pragma unroll
    for (int off = 32; off > 0; off >>= 1) s += __shfl_down(s, off, 64);
    if (lane == 0) c2p[r] = s * 524288.f;  // 2^19

    const float e[8] = {a.x, a.y, a.z, a.w, c.x, c.y, c.z, c.w};
    half8 hv, lv;
#pragma unroll
    for (int i = 0; i < 8; ++i) {
        float v = e[i] * 1024.f;
        _Float16 h = (_Float16)v;
        hv[i] = h;
        lv[i] = (_Float16)(v - (float)h);
    }
    *(half8*)(y + (size_t)r * 1024 + lane * 8) = hv;
    *(half8*)(y + (size_t)r * 1024 + 512 + lane * 8) = lv;
}

// ---------------- MFMA cross-GEMM + fused argmin, 256l x 256v, 32x32x16 shape ------
// Same 4-phase R10 schedule/staging; compute core switched to v_mfma_f32_32x32x16_f16:
// half the MFMA instructions (48/wave/step) at the higher 32x32 rate (m06: 2382 TF).
// Wave tile 64l x 128v = 2 mtiles x 4 ntiles of 32x32; acc = floatx16[2][4].
// Fragments: A row = lane&31, k = (lane>>5)*8+i (32-lane analog of the verified
// 16x16 pattern); B col = lane&31, same k; C/D col=lane&31,
// row=(reg&3)+8*(reg>>2)+4*(lane>>5) [m74/m101]. LDS layout/staging unchanged;
// read seg = (ks*2+g) ^ ((row>>1)&3) keeps the rule-21 involution.
// Phase p: (ks=p>>1, ntile pair {2*(p&1), 2*(p&1)+1}) -> 12 MFMA, 4 acc chains.
__global__ __launch_bounds__(512, 2) void cross_mfma_kernel(
    const _Float16* __restrict__ Af, const _Float16* __restrict__ Bf,
    const float* __restrict__ c2p,
    int* __restrict__ tok_i, float* __restrict__ tok_f) {

    __shared__ _Float16 AsH[2][8192], AsL[2][8192];   // 16 KB per plane per buf
    __shared__ _Float16 BsH[2][8192], BsL[2][8192];   // 16 KB per plane per buf
    __shared__ float c2s[2048];
    __shared__ float slotv[2][256];
    __shared__ int   sloti[2][256];

    const int tid  = threadIdx.x;
    const int w    = tid >> 6;        // 0..7
    const int lane = tid & 63;
    const int wm = w >> 1;            // 0..3: 64-row band
    const int wn = w & 1;             // 0..1: 128-col band
    const int g    = lane >> 5;       // k-group (0/1)
    const int cl32 = lane & 31;       // row/col within 32-tile

    const int l0 = blockIdx.x * 256;
    const int k  = blockIdx.y;
    const int b  = blockIdx.z;

    const _Float16* Ab = Af + (size_t)(b * L3V + l0) * 1024;
    const _Float16* Bb = Bf + (size_t)k * VOCABV * 1024;

    // prologue: c2 -> LDS; slot init (published by step-0 barrier)
    {
        float4 cv = *(const float4*)&c2p[k * VOCABV + tid * 4];
        *(float4*)&c2s[tid * 4] = cv;
    }
    if (tid < 256) {
        slotv[0][tid] = -3.4e38f; slotv[1][tid] = -3.4e38f;
        sloti[0][tid] = 0;        sloti[1][tid] = 0;
    }

    // staging geometry (unchanged from R10)
    const int arow  = w * 16 + (lane >> 2);
    const int bg    = (w >> 1) & 1;
    const int bj    = (w & 1) * 16 + (lane >> 2);
    const int bpl   = w >> 2;
    const int sswz8 = ((lane & 3) ^ ((lane >> 3) & 3)) * 8;
    // fragment-read swizzled seg offset (halfs) for ks=0; ks=1 is ^16
    const int oK0   = (g ^ ((cl32 >> 1) & 3)) * 8;

#define STAGE_A(NXT, KON, PL, H) do { \
    const _Float16* s_ = Ab + (size_t)((H) * 128 + arow) * 1024 + (PL) * 512 + (KON) + sswz8; \
    gload_lds16(s_, ((PL) ? (char*)&AsL[NXT][0] : (char*)&AsH[NXT][0]) \
                     + (H) * 8192 + w * 1024 + lane * 16); \
} while (0)
#define STAGE_B(NXT, VTN, KON, C) do { \
    const _Float16* s_ = Bb + (size_t)((VTN) * 256 + 128 * bg + 32 * (C) + bj) * 1024 \
                         + bpl * 512 + (KON) + sswz8; \
    gload_lds16(s_, (bpl ? (char*)&BsL[NXT][0] : (char*)&BsH[NXT][0]) \
                     + (C) * 4096 + (w & 3) * 1024 + lane * 16); \
} while (0)

    // read B fragment of ntile NT at ksub KS (hi+lo) from buf cur
#define READ_B32(NT, KS, H, L) do { \
    const int bro_ = ((NT) * 64 + wn * 32 + cl32) * 32 + (oK0 ^ ((KS) * 16)); \
    H = *(const half8*)&BsH[cur][bro_]; \
    L = *(const half8*)&BsL[cur][bro_]; \
} while (0)

    // 12 MFMAs: ntiles NT0,NT1 at ksub KS; 4 independent acc chains (2mt x 2nt)
#define MFMA_P(KS, NT0, NT1, BH0, BL0, BH1, BL1) do { \
    __builtin_amdgcn_s_setprio(1); \
    _Pragma("unroll") \
    for (int mt = 0; mt < 2; ++mt) { \
        acc[mt][NT0] = __builtin_amdgcn_mfma_f32_32x32x16_f16(ah[mt][KS], BH0, acc[mt][NT0], 0, 0, 0); \
        acc[mt][NT1] = __builtin_amdgcn_mfma_f32_32x32x16_f16(ah[mt][KS], BH1, acc[mt][NT1], 0, 0, 0); \
        acc[mt][NT0] = __builtin_amdgcn_mfma_f32_32x32x16_f16(al[mt][KS], BH0, acc[mt][NT0], 0, 0, 0); \
        acc[mt][NT1] = __builtin_amdgcn_mfma_f32_32x32x16_f16(al[mt][KS], BH1, acc[mt][NT1], 0, 0, 0); \
        acc[mt][NT0] = __builtin_amdgcn_mfma_f32_32x32x16_f16(ah[mt][KS], BL0, acc[mt][NT0], 0, 0, 0); \
        acc[mt][NT1] = __builtin_amdgcn_mfma_f32_32x32x16_f16(ah[mt][KS], BL1, acc[mt][NT1], 0, 0, 0); \
    } \
    __builtin_amdgcn_s_setprio(0); \
    __builtin_amdgcn_sched_barrier(0); \
} while (0)

    floatx16 acc[2][4];
    half8 ah[2][2], al[2][2];   // [mt][ks]
    int cur = 0;

    // prologue stage: all 8 loads for step 0 (one-time burst)
    STAGE_A(0, 0, 0, 0); STAGE_A(0, 0, 0, 1);
    STAGE_A(0, 0, 1, 0); STAGE_A(0, 0, 1, 1);
    STAGE_B(0, 0, 0, 0); STAGE_B(0, 0, 0, 1);
    STAGE_B(0, 0, 0, 2); STAGE_B(0, 0, 0, 3);

#pragma unroll 1
    for (int t = 0; t < 128; ++t) {
        const int nxt = cur ^ 1;
        const int tn  = t + 1;
        const int vtn = tn >> 4;
        const int kon = (tn & 15) << 5;
        const int vt  = t >> 4;

        if ((t & 15) == 0) {
#pragma unroll
            for (int mt = 0; mt < 2; ++mt)
#pragma unroll
                for (int nt = 0; nt < 4; ++nt)
#pragma unroll
                    for (int r = 0; r < 16; ++r) acc[mt][nt][r] = 0.f;
        }

        // ---- step-top publication: buf[cur] fully visible after this barrier ----
        asm volatile("s_waitcnt vmcnt(0)" ::: "memory");
        __builtin_amdgcn_s_barrier();

        half8 s0h0, s0l0, s0h1, s0l1, s1h0, s1l0, s1h1, s1l1;

        // phase 0: A frags (all mt,ks) + B ntiles 0,1 @ ks0
#pragma unroll
        for (int mt = 0; mt < 2; ++mt)
#pragma unroll
            for (int ks = 0; ks < 2; ++ks) {
                const int aro = (wm * 64 + mt * 32 + cl32) * 32 + (oK0 ^ (ks * 16));
                ah[mt][ks] = *(const half8*)&AsH[cur][aro];
                al[mt][ks] = *(const half8*)&AsL[cur][aro];
            }
        READ_B32(0, 0, s0h0, s0l0);
        READ_B32(1, 0, s0h1, s0l1);
        if (t < 127) { STAGE_A(nxt, kon, 0, 0); STAGE_A(nxt, kon, 0, 1); }
        asm volatile("s_waitcnt lgkmcnt(0)" ::: "memory");
        __builtin_amdgcn_sched_barrier(0);
        MFMA_P(0, 0, 1, s0h0, s0l0, s0h1, s0l1);
        READ_B32(2, 0, s1h0, s1l0);
        READ_B32(3, 0, s1h1, s1l1);
        if (t < 127) { STAGE_A(nxt, kon, 1, 0); STAGE_A(nxt, kon, 1, 1); }
        __builtin_amdgcn_sched_barrier(0);

        __builtin_amdgcn_s_barrier();          // phase 1 alignment
        asm volatile("s_waitcnt lgkmcnt(0)" ::: "memory");
        __builtin_amdgcn_sched_barrier(0);
        MFMA_P(0, 2, 3, s1h0, s1l0, s1h1, s1l1);
        READ_B32(0, 1, s0h0, s0l0);            // set0 free (ks0 nt0/1 consumed)
        READ_B32(1, 1, s0h1, s0l1);
        if (t < 127) { STAGE_B(nxt, vtn, kon, 0); STAGE_B(nxt, vtn, kon, 1); }
        __builtin_amdgcn_sched_barrier(0);

        __builtin_amdgcn_s_barrier();          // phase 2 alignment
        asm volatile("s_waitcnt lgkmcnt(0)" ::: "memory");
        __builtin_amdgcn_sched_barrier(0);
        MFMA_P(1, 0, 1, s0h0, s0l0, s0h1, s0l1);
        READ_B32(2, 1, s1h0, s1l0);            // set1 free
        READ_B32(3, 1, s1h1, s1l1);
        if (t < 127) { STAGE_B(nxt, vtn, kon, 2); STAGE_B(nxt, vtn, kon, 3); }
        __builtin_amdgcn_sched_barrier(0);

        __builtin_amdgcn_s_barrier();          // phase 3 alignment
        asm volatile("s_waitcnt lgkmcnt(0)" ::: "memory");
        __builtin_amdgcn_sched_barrier(0);
        MFMA_P(1, 2, 3, s1h0, s1l0, s1h1, s1l1);
        cur = nxt;

        if ((t & 15) == 15) {
            // per-vt argmax epilogue (c2 from LDS; no VMEM here)
            float c2v[4];
#pragma unroll
            for (int nt = 0; nt < 4; ++nt)
                c2v[nt] = c2s[vt * 256 + wn * 128 + nt * 32 + cl32];
#pragma unroll
            for (int mt = 0; mt < 2; ++mt)
#pragma unroll
                for (int r = 0; r < 16; ++r) {
                    float bv = acc[mt][0][r] - c2v[0];
                    int   bi = vt * 256 + wn * 128 + cl32;
#pragma unroll
                    for (int nt = 1; nt < 4; ++nt) {
                        float m = acc[mt][nt][r] - c2v[nt];
                        int   vi = vt * 256 + wn * 128 + nt * 32 + cl32;
                        if (m > bv) { bv = m; bi = vi; }
                    }
#pragma unroll
                    for (int msk = 1; msk < 32; msk <<= 1) {
                        float ov = __shfl_xor(bv, msk, 64);
                        int   oi = __shfl_xor(bi, msk, 64);
                        if (ov > bv || (ov == bv && oi < bi)) { bv = ov; bi = oi; }
                    }
                    if (cl32 == 0) {
                        const int row = wm * 64 + mt * 32 + (r & 3) + 8 * (r >> 2) + 4 * g;
                        float cur_v = slotv[wn][row];
                        int   ci  = sloti[wn][row];
                        if (bv > cur_v || (bv == cur_v && bi < ci)) {
                            slotv[wn][row] = bv;
                            sloti[wn][row] = bi;
                        }
                    }
                }
        }
    }
#undef MFMA_P
#undef READ_B32
#undef STAGE_A
#undef STAGE_B

    __syncthreads();
    if (tid < 256) {
        float v0 = slotv[0][tid], v1 = slotv[1][tid];
        int   i0 = sloti[0][tid], i1 = sloti[1][tid];
        bool t1 = (v1 > v0);  // wn=1 indices always larger: ties keep wn=0
        int best = t1 ? i1 : i0;
        const int n = (b * KCB + k) * L3V + l0 + tid;
        tok_i[n] = best;
        tok_f[n] = (float)best;
    }
}

// ---------------- embedding mean over 4 codebooks ----------------
__global__ void emb_kernel(const int* __restrict__ tokens, const float* __restrict__ E,
                           float* __restrict__ out) {
    const int l = blockIdx.x;
    const int b = blockIdx.y;
    const int h4 = threadIdx.x * 4;
    const int t0 = tokens[((size_t)(b * KCB + 0)) * L3V + l];
    const int t1 = tokens[((size_t)(b * KCB + 1)) * L3V + l];
    const int t2 = tokens[((size_t)(b * KCB + 2)) * L3V + l];
    const int t3 = tokens[((size_t)(b * KCB + 3)) * L3V + l];
    const float4 e0 = *(const float4*)&E[(size_t)t0 * 512 + h4];
    const float4 e1 = *(const float4*)&E[(size_t)t1 * 512 + h4];
    const float4 e2 = *(const float4*)&E[(size_t)t2 * 512 + h4];
    const float4 e3 = *(const float4*)&E[(size_t)t3 * 512 + h4];
    float4 r;
    r.x = (e0.x + e1.x + e2.x + e3.x) * 0.25f;
    r.y = (e0.y + e1.y + e2.y + e3.y) * 0.25f;
    r.z = (e0.z + e1.z + e2.z + e3.z) * 0.25f;
    r.w = (e0.w + e1.w + e2.w + e3.w) * 0.25f;
    *(float4*)&out[((size_t)b * L3V + l) * 512 + h4] = r;
}

extern "C" void kernel_launch(void* const* d_in, const int* in_sizes, int n_in,
                              void* d_out, int out_size, void* d_ws, size_t ws_size,
                              hipStream_t stream) {
    const float* audio = (const float*)d_in[0];
    const float* w1 = (const float*)d_in[1];
    const float* b1 = (const float*)d_in[2];
    const float* w2 = (const float*)d_in[3];
    const float* b2 = (const float*)d_in[4];
    const float* w3 = (const float*)d_in[5];
    const float* b3 = (const float*)d_in[6];
    const float* cb = (const float*)d_in[7];
    const float* E  = (const float*)d_in[8];

    float* out_tok = (float*)d_out;
    float* out_emb = out_tok + (size_t)B_ * KCB * L3V;

    float* ws = (float*)d_ws;
    size_t off = 0;
    float* x1f = ws + off; off += (size_t)B_ * C1V * (L1V + 16);
    float* x2f = ws + off; off += (size_t)B_ * C2V * (L2V + 16);
    float* w2h_f = ws + off; off += (size_t)C2V * (C1V * 8) / 2;
    float* w2l_f = ws + off; off += (size_t)C2V * (C1V * 8) / 2;
    float* w3h_f = ws + off; off += (size_t)C3V * (C2V * 8) / 2;
    float* w3l_f = ws + off; off += (size_t)C3V * (C2V * 8) / 2;
    float* c2p = ws + off; off += (size_t)KCB * VOCABV;
    int*   tok = (int*)(ws + off); off += (size_t)B_ * KCB * L3V;

    _Float16* X1  = (_Float16*)x1f;
    _Float16* X2  = (_Float16*)x2f;
    _Float16* Afh = (_Float16*)x1f;   // conv3 writes over x1 (dead after conv2)
    _Float16* Bfh = (_Float16*)x2f;   // cbprep writes over x2 (dead after conv3)
    _Float16* W2H = (_Float16*)w2h_f; _Float16* W2L = (_Float16*)w2l_f;
    _Float16* W3H = (_Float16*)w3h_f; _Float16* W3L = (_Float16*)w3l_f;

    padzero_kernel<<<24, 256, 0, stream>>>(X1, X2);

    wsplit_kernel<<<(C2V * C1V + 255) / 256, 256, 0, stream>>>(w2, W2H, W2L, C1V, C2V);
    wsplit_kernel<<<(C3V * C2V + 255) / 256, 256, 0, stream>>>(w3, W3H, W3L, C2V, C3V);

    conv1_kernel<<<dim3(L1V / 256, C1V, B_), 256, 0, stream>>>(audio, w1, b1, X1);

    conv2_mfma_kernel<<<dim3(L2V / 128, C2V / 128, B_), 256, 0, stream>>>(
        X1, W2H, W2L, b2, X2);

    conv3_mfma_kernel<<<dim3(L3V / 128, C3V / 128, B_), 256, 0, stream>>>(
        X2, W3H, W3L, b3, Afh);

    cbprep_kernel<<<KCB * VOCABV, 64, 0, stream>>>(cb, Bfh, c2p);

    cross_mfma_kernel<<<dim3(L3V / 256, KCB, B_), 512, 0, stream>>>(
        Afh, Bfh, c2p, tok, out_tok);

    emb_kernel<<<dim3(L3V, B_), 128, 0, stream>>>(tok, E, out_emb);
}

// Round 12
// 602.629 us; speedup vs baseline: 1.2237x; 1.2237x over previous
//
#include <hip/hip_runtime.h>
#include <hip/hip_bf16.h>
#include <stdint.h>

#define B_ 4
#define S_IN 32768
#define C1V 128
#define L1V 16384
#define C2V 256
#define L2V 8192
#define C3V 512
#define L3V 4096
#define VOCABV 2048
#define KCB 4

// padded hi/lo f16 plane layout for conv activations:
// row r = b*C + c, row stride R = 2*(L+16) halfs; hi plane at [8 .. L+8), lo at +P=(L+16).
// 8-half zero pads on both sides of each plane allow unpredicated global_load_lds staging.
#define R1P (2 * (L1V + 16))
#define P1P (L1V + 16)
#define R2P (2 * (L2V + 16))
#define P2P (L2V + 16)

typedef _Float16 half8 __attribute__((ext_vector_type(8)));
typedef float floatx4 __attribute__((ext_vector_type(4)));

#define AS1 __attribute__((address_space(1)))
#define AS3 __attribute__((address_space(3)))

__device__ __forceinline__ void gload_lds16(const void* g, void* l) {
    __builtin_amdgcn_global_load_lds((const AS1 void*)g, (AS3 void*)l, 16, 0, 0);
}

// read 8 halfs at a 4B-aligned LDS address (4x ds_read_b32)
__device__ __forceinline__ half8 lds_read_half8_a4(const _Float16* p) {
    union { uint32_t u[4]; half8 h; } t;
    const uint32_t* w = (const uint32_t*)p;
    t.u[0] = w[0]; t.u[1] = w[1]; t.u[2] = w[2]; t.u[3] = w[3];
    return t.h;
}

// ---------------- pad zeroing for x1/x2 hi-lo buffers (runs first) ----------------
__global__ void padzero_kernel(_Float16* __restrict__ x1h, _Float16* __restrict__ x2h) {
    int j = blockIdx.x * 256 + threadIdx.x;
    half8 z;
#pragma unroll
    for (int i = 0; i < 8; ++i) z[i] = (_Float16)0.f;
    if (j < 2048) {                       // B*C1V=512 rows x 4 pad-slots
        int row = j >> 2, p = j & 3;
        size_t base = (size_t)row * R1P + (size_t)(p >> 1) * P1P + ((p & 1) ? (L1V + 8) : 0);
        *(half8*)(x1h + base) = z;
    } else if (j < 6144) {                // B*C2V=1024 rows x 4 pad-slots
        int j2 = j - 2048;
        int row = j2 >> 2, p = j2 & 3;
        size_t base = (size_t)row * R2P + (size_t)(p >> 1) * P2P + ((p & 1) ? (L2V + 8) : 0);
        *(half8*)(x2h + base) = z;
    }
}

// ---------------- conv1: [B,1,S] -> padded hi/lo f16 planes, k=7 s=2 p=3, relu -----
__global__ void conv1_kernel(const float* __restrict__ x, const float* __restrict__ w,
                             const float* __restrict__ bias, _Float16* __restrict__ out) {
    __shared__ float xs[2 * 256 + 6];
    __shared__ float ws[7];
    const int l0 = blockIdx.x * 256;
    const int co = blockIdx.y;
    const int b  = blockIdx.z;
    const int tid = threadIdx.x;
    const float* xb = x + (size_t)b * S_IN;
    for (int n = tid; n < 2 * 256 + 6; n += 256) {
        int p = 2 * l0 - 3 + n;
        xs[n] = (p >= 0 && p < S_IN) ? xb[p] : 0.f;
    }
    if (tid < 7) ws[tid] = w[co * 7 + tid];
    __syncthreads();
    float acc = bias[co];
    const int base = 2 * tid;
#pragma unroll
    for (int t = 0; t < 7; ++t) acc = fmaf(ws[t], xs[base + t], acc);
    float s = fmaxf(acc, 0.f) * 1024.f;   // pre-scaled x1024, split hi/lo (exact 2^10 scale)
    _Float16 h  = (_Float16)s;
    _Float16 lo = (_Float16)(s - (float)h);
    size_t o = (size_t)(b * C1V + co) * R1P + 8 + l0 + tid;
    out[o] = h;
    out[o + P1P] = lo;
}

// ---------------- weight prep: w[co][ci][7] fp32 -> hi/lo f16 planes [co][ci*8+u] ----
__global__ void wsplit_kernel(const float* __restrict__ w, _Float16* __restrict__ wh,
                              _Float16* __restrict__ wl, int cin, int cout) {
    int idx = blockIdx.x * 256 + threadIdx.x;
    if (idx >= cin * cout) return;
    int co = idx / cin;
    int ci = idx - co * cin;
    const float* src = w + ((size_t)co * cin + ci) * 7;
    half8 h, l;
    h[0] = (_Float16)0.f; l[0] = (_Float16)0.f;
#pragma unroll
    for (int u = 1; u < 8; ++u) {
        float v = src[u - 1] * 1024.f;
        _Float16 hh = (_Float16)v;
        h[u] = hh;
        l[u] = (_Float16)(v - (float)hh);
    }
    size_t o = (size_t)co * (cin * 8) + ci * 8;
    *(half8*)(wh + o) = h;
    *(half8*)(wl + o) = l;
}

// X staging (both convs): 272 16B-segs = [pl(2)][ci(4)][sg(34)] -> flat LDS Xs[2176].
// 34 segs cover 272 halfs/row starting at window base p = 2*l0-8 (buffer idx 2*l0, pads absorb OOB).
// Fragment reads shift +4 vs the old m-indexing: Xs[pl*1088 + ci*272 + 4 + 2*lrel].
// W tiles keep the rule-21 swizzle: source seg ^= (row>>1)&3; read seg ^= (cl>>1)&3.

// ---------------- conv2 via f16 3-product MFMA: A=W (m=co), B=X windows (n=l) -------
__global__ __launch_bounds__(256, 2) void conv2_mfma_kernel(
    const _Float16* __restrict__ xin, const _Float16* __restrict__ WH,
    const _Float16* __restrict__ WL, const float* __restrict__ bias,
    _Float16* __restrict__ xout) {
    __shared__ _Float16 Xs[2176];
    __shared__ _Float16 WsH[128 * 32], WsL[128 * 32];
    const int tid = threadIdx.x;
    const int wave = tid >> 6;
    const int lane = tid & 63;
    const int wm = wave >> 1, wn = wave & 1;
    const int q  = lane >> 4;
    const int cl = lane & 15;
    const int l0  = blockIdx.x * 128;
    const int co0 = blockIdx.y * 128;
    const int b   = blockIdx.z;

    const int wrow  = lane >> 2;
    const int wseg  = lane & 3;
    const int wsoff = (wseg ^ ((wrow >> 1) & 3)) * 8;   // swizzled source offset (halfs)
    const int rq    = (q ^ ((cl >> 1) & 3)) * 8;        // swizzled read offset (halfs)

    // X seg decomposition (this thread's seg = tid; tail segs 256..271 on lanes 0..15)
    const int pl0 = (tid >= 136) ? 1 : 0;
    const int r0  = tid - pl0 * 136;
    const int ci0 = r0 / 34;
    const int sg0 = r0 - ci0 * 34;
    const _Float16* xb = xin + (size_t)b * C1V * R1P;

    floatx4 acc[4][4];
#pragma unroll
    for (int a = 0; a < 4; ++a)
#pragma unroll
        for (int n = 0; n < 4; ++n) acc[a][n] = (floatx4){0.f, 0.f, 0.f, 0.f};

    for (int ch = 0; ch < 32; ++ch) {
        __syncthreads();
        {   // X: 272 segs via global_load_lds (no VALU conversion)
            const _Float16* gx = xb + (size_t)(ch * 4 + ci0) * R1P + pl0 * P1P + 2 * l0 + sg0 * 8;
            gload_lds16(gx, (char*)Xs + (tid & ~63) * 16);
            if (tid < 16) {  // tail: pl=1, ci=3, sg=18+tid
                const _Float16* gt = xb + (size_t)(ch * 4 + 3) * R1P + P1P + 2 * l0 + (18 + tid) * 8;
                gload_lds16(gt, (char*)Xs + 4096);
            }
        }
        const int k0 = ch * 32;
        for (int g = wave; g < 8; g += 4) {
            const _Float16* gh = WH + (size_t)(co0 + g * 16 + wrow) * 1024 + k0 + wsoff;
            const _Float16* gl = WL + (size_t)(co0 + g * 16 + wrow) * 1024 + k0 + wsoff;
            gload_lds16(gh, (char*)WsH + g * 1024);
            gload_lds16(gl, (char*)WsL + g * 1024);
        }
        asm volatile("s_waitcnt vmcnt(0)" ::: "memory");
        __syncthreads();

        half8 awh[4], awl[4], bxh[4], bxl[4];
#pragma unroll
        for (int a = 0; a < 4; ++a) {
            const int ro = (wm * 64 + a * 16 + cl) * 32 + rq;
            awh[a] = *(const half8*)&WsH[ro];
            awl[a] = *(const half8*)&WsL[ro];
        }
#pragma unroll
        for (int n = 0; n < 4; ++n) {
            const int lrel = wn * 64 + n * 16 + cl;
            bxh[n] = lds_read_half8_a4(&Xs[q * 272 + 4 + 2 * lrel]);
            bxl[n] = lds_read_half8_a4(&Xs[1088 + q * 272 + 4 + 2 * lrel]);
        }
#pragma unroll
        for (int a = 0; a < 4; ++a)
#pragma unroll
            for (int n = 0; n < 4; ++n) {
                acc[a][n] = __builtin_amdgcn_mfma_f32_16x16x32_f16(awh[a], bxh[n], acc[a][n], 0, 0, 0);
                acc[a][n] = __builtin_amdgcn_mfma_f32_16x16x32_f16(awl[a], bxh[n], acc[a][n], 0, 0, 0);
                acc[a][n] = __builtin_amdgcn_mfma_f32_16x16x32_f16(awh[a], bxl[n], acc[a][n], 0, 0, 0);
            }
    }

    float bv[4][4];
#pragma unroll
    for (int a = 0; a < 4; ++a)
#pragma unroll
        for (int r = 0; r < 4; ++r) bv[a][r] = bias[co0 + wm * 64 + a * 16 + q * 4 + r];
#pragma unroll
    for (int a = 0; a < 4; ++a)
#pragma unroll
        for (int n = 0; n < 4; ++n) {
            const int l = l0 + wn * 64 + n * 16 + cl;
#pragma unroll
            for (int r = 0; r < 4; ++r) {
                const int co = co0 + wm * 64 + a * 16 + q * 4 + r;
                float vv = fmaxf(acc[a][n][r] * (1.f / 1048576.f) + bv[a][r], 0.f);
                float s = vv * 1024.f;               // pre-scaled hi/lo for conv3 staging
                _Float16 h  = (_Float16)s;
                _Float16 lo = (_Float16)(s - (float)h);
                size_t o = (size_t)(b * C2V + co) * R2P + 8 + l;
                xout[o] = h;
                xout[o + P2P] = lo;
            }
        }
}

// ---------------- conv3 via f16 3-product MFMA: A=X windows (m=l), B=W (n=co) -------
__global__ __launch_bounds__(256, 2) void conv3_mfma_kernel(
    const _Float16* __restrict__ xin, const _Float16* __restrict__ WH,
    const _Float16* __restrict__ WL, const float* __restrict__ bias,
    _Float16* __restrict__ outh) {
    __shared__ _Float16 Xs[2176];
    __shared__ _Float16 WsH[128 * 32], WsL[128 * 32];
    const int tid = threadIdx.x;
    const int wave = tid >> 6;
    const int lane = tid & 63;
    const int wm = wave >> 1, wn = wave & 1;
    const int q  = lane >> 4;
    const int cl = lane & 15;
    const int l0  = blockIdx.x * 128;
    const int co0 = blockIdx.y * 128;
    const int b   = blockIdx.z;

    const int wrow  = lane >> 2;
    const int wseg  = lane & 3;
    const int wsoff = (wseg ^ ((wrow >> 1) & 3)) * 8;
    const int rq    = (q ^ ((cl >> 1) & 3)) * 8;

    const int pl0 = (tid >= 136) ? 1 : 0;
    const int r0  = tid - pl0 * 136;
    const int ci0 = r0 / 34;
    const int sg0 = r0 - ci0 * 34;
    const _Float16* xb = xin + (size_t)b * C2V * R2P;

    floatx4 acc[4][4];
#pragma unroll
    for (int a = 0; a < 4; ++a)
#pragma unroll
        for (int n = 0; n < 4; ++n) acc[a][n] = (floatx4){0.f, 0.f, 0.f, 0.f};

    for (int ch = 0; ch < 64; ++ch) {
        __syncthreads();
        {
            const _Float16* gx = xb + (size_t)(ch * 4 + ci0) * R2P + pl0 * P2P + 2 * l0 + sg0 * 8;
            gload_lds16(gx, (char*)Xs + (tid & ~63) * 16);
            if (tid < 16) {
                const _Float16* gt = xb + (size_t)(ch * 4 + 3) * R2P + P2P + 2 * l0 + (18 + tid) * 8;
                gload_lds16(gt, (char*)Xs + 4096);
            }
        }
        const int k0 = ch * 32;
        for (int g = wave; g < 8; g += 4) {
            const _Float16* gh = WH + (size_t)(co0 + g * 16 + wrow) * 2048 + k0 + wsoff;
            const _Float16* gl = WL + (size_t)(co0 + g * 16 + wrow) * 2048 + k0 + wsoff;
            gload_lds16(gh, (char*)WsH + g * 1024);
            gload_lds16(gl, (char*)WsL + g * 1024);
        }
        asm volatile("s_waitcnt vmcnt(0)" ::: "memory");
        __syncthreads();

        half8 axh[4], axl[4], bwh[4], bwl[4];
#pragma unroll
        for (int a = 0; a < 4; ++a) {
            const int lrel = wm * 64 + a * 16 + cl;
            axh[a] = lds_read_half8_a4(&Xs[q * 272 + 4 + 2 * lrel]);
            axl[a] = lds_read_half8_a4(&Xs[1088 + q * 272 + 4 + 2 * lrel]);
        }
#pragma unroll
        for (int n = 0; n < 4; ++n) {
            const int ro = (wn * 64 + n * 16 + cl) * 32 + rq;
            bwh[n] = *(const half8*)&WsH[ro];
            bwl[n] = *(const half8*)&WsL[ro];
        }
#pragma unroll
        for (int a = 0; a < 4; ++a)
#pragma unroll
            for (int n = 0; n < 4; ++n) {
                acc[a][n] = __builtin_amdgcn_mfma_f32_16x16x32_f16(axh[a], bwh[n], acc[a][n], 0, 0, 0);
                acc[a][n] = __builtin_amdgcn_mfma_f32_16x16x32_f16(axl[a], bwh[n], acc[a][n], 0, 0, 0);
                acc[a][n] = __builtin_amdgcn_mfma_f32_16x16x32_f16(axh[a], bwl[n], acc[a][n], 0, 0, 0);
            }
    }

    float bv[4];
#pragma unroll
    for (int n = 0; n < 4; ++n) bv[n] = bias[co0 + wn * 64 + n * 16 + cl];
#pragma unroll
    for (int a = 0; a < 4; ++a)
#pragma unroll
        for (int n = 0; n < 4; ++n) {
            const int co = co0 + wn * 64 + n * 16 + cl;
#pragma unroll
            for (int r = 0; r < 4; ++r) {
                const int l = l0 + wm * 64 + a * 16 + q * 4 + r;
                float f = acc[a][n][r] * (1.f / 1048576.f) + bv[n];
                float s = f * 1024.f;
                _Float16 h = (_Float16)s;
                _Float16 lo = (_Float16)(s - (float)h);
                _Float16* dst = outh + ((size_t)b * L3V + l) * 1024 + co;
                dst[0] = h;
                dst[512] = lo;
            }
        }
}

// ---------------- fused codebook prep: rowsq*2^19 + x1024 hi/lo f16 split ----------
__global__ void cbprep_kernel(const float* __restrict__ cb, _Float16* __restrict__ y,
                              float* __restrict__ c2p) {
    const int r = blockIdx.x;
    const int lane = threadIdx.x;  // 64
    const float* row = cb + (size_t)r * 512;
    float4 a = *(const float4*)&row[lane * 8];
    float4 c = *(const float4*)&row[lane * 8 + 4];
    float s = a.x * a.x + a.y * a.y + a.z * a.z + a.w * a.w
            + c.x * c.x + c.y * c.y + c.z * c.z + c.w * c.w;
#pragma unroll
    for (int off = 32; off > 0; off >>= 1) s += __shfl_down(s, off, 64);
    if (lane == 0) c2p[r] = s * 524288.f;  // 2^19

    const float e[8] = {a.x, a.y, a.z, a.w, c.x, c.y, c.z, c.w};
    half8 hv, lv;
#pragma unroll
    for (int i = 0; i < 8; ++i) {
        float v = e[i] * 1024.f;
        _Float16 h = (_Float16)v;
        hv[i] = h;
        lv[i] = (_Float16)(v - (float)h);
    }
    *(half8*)(y + (size_t)r * 1024 + lane * 8) = hv;
    *(half8*)(y + (size_t)r * 1024 + 512 + lane * 8) = lv;
}

// ---------------- MFMA cross-GEMM + fused argmin, 256l x 256v, 4-phase schedule ----
// R10-verified (cross = 377 us, 0 bank conflicts, MfmaUtil ~51). Best-known state.
__global__ __launch_bounds__(512, 2) void cross_mfma_kernel(
    const _Float16* __restrict__ Af, const _Float16* __restrict__ Bf,
    const float* __restrict__ c2p,
    int* __restrict__ tok_i, float* __restrict__ tok_f) {

    __shared__ _Float16 AsH[2][8192], AsL[2][8192];   // 16 KB per plane per buf
    __shared__ _Float16 BsH[2][8192], BsL[2][8192];   // 16 KB per plane per buf
    __shared__ float c2s[2048];
    __shared__ float slotv[2][256];
    __shared__ int   sloti[2][256];

    const int tid  = threadIdx.x;
    const int w    = tid >> 6;        // 0..7
    const int lane = tid & 63;
    const int wm = w >> 1;            // 0..3: 64-row band
    const int wn = w & 1;             // 0..1: 128-col band
    const int q  = lane >> 4;
    const int cl = lane & 15;

    const int l0 = blockIdx.x * 256;
    const int k  = blockIdx.y;
    const int b  = blockIdx.z;

    const _Float16* Ab = Af + (size_t)(b * L3V + l0) * 1024;
    const _Float16* Bb = Bf + (size_t)k * VOCABV * 1024;

    // prologue: c2 -> LDS; slot init (published by step-0 barrier)
    {
        float4 cv = *(const float4*)&c2p[k * VOCABV + tid * 4];
        *(float4*)&c2s[tid * 4] = cv;
    }
    if (tid < 256) {
        slotv[0][tid] = -3.4e38f; slotv[1][tid] = -3.4e38f;
        sloti[0][tid] = 0;        sloti[1][tid] = 0;
    }

    // staging geometry (per-lane constants)
    const int arow  = w * 16 + (lane >> 2);            // A: row within 128-half
    const int bg    = (w >> 1) & 1;                    // B: wn-group
    const int bj    = (w & 1) * 16 + (lane >> 2);      // B: row within 32-group
    const int bpl   = w >> 2;                          // B: plane (0=hi,1=lo)
    const int sswz8 = ((lane & 3) ^ ((lane >> 3) & 3)) * 8;  // swizzled src seg (halfs)
    const int brq   = (q ^ ((cl >> 1) & 3)) * 8;       // swizzled read seg (halfs)

#define STAGE_A(NXT, KON, PL, H) do { \
    const _Float16* s_ = Ab + (size_t)((H) * 128 + arow) * 1024 + (PL) * 512 + (KON) + sswz8; \
    gload_lds16(s_, ((PL) ? (char*)&AsL[NXT][0] : (char*)&AsH[NXT][0]) \
                     + (H) * 8192 + w * 1024 + lane * 16); \
} while (0)
#define STAGE_B(NXT, VTN, KON, C) do { \
    const _Float16* s_ = Bb + (size_t)((VTN) * 256 + 128 * bg + 32 * (C) + bj) * 1024 \
                         + bpl * 512 + (KON) + sswz8; \
    gload_lds16(s_, (bpl ? (char*)&BsL[NXT][0] : (char*)&BsH[NXT][0]) \
                     + (C) * 4096 + (w & 3) * 1024 + lane * 16); \
} while (0)

    // read both nt-columns of B chunk P from buf cur into 4 half8 regs
#define READ_B(P, H0, L0, H1, L1) do { \
    const int bro_ = (P) * 2048 + wn * 1024 + cl * 32 + brq; \
    H0 = *(const half8*)&BsH[cur][bro_]; \
    L0 = *(const half8*)&BsL[cur][bro_]; \
    H1 = *(const half8*)&BsH[cur][bro_ + 512]; \
    L1 = *(const half8*)&BsL[cur][bro_ + 512]; \
} while (0)

#define MFMA_CHUNK(P, H0, L0, H1, L1) do { \
    __builtin_amdgcn_s_setprio(1); \
    _Pragma("unroll") \
    for (int mt = 0; mt < 4; ++mt) { \
        acc[mt][2*(P)]   = __builtin_amdgcn_mfma_f32_16x16x32_f16(ah[mt], H0, acc[mt][2*(P)], 0, 0, 0); \
        acc[mt][2*(P)]   = __builtin_amdgcn_mfma_f32_16x16x32_f16(al[mt], H0, acc[mt][2*(P)], 0, 0, 0); \
        acc[mt][2*(P)]   = __builtin_amdgcn_mfma_f32_16x16x32_f16(ah[mt], L0, acc[mt][2*(P)], 0, 0, 0); \
        acc[mt][2*(P)+1] = __builtin_amdgcn_mfma_f32_16x16x32_f16(ah[mt], H1, acc[mt][2*(P)+1], 0, 0, 0); \
        acc[mt][2*(P)+1] = __builtin_amdgcn_mfma_f32_16x16x32_f16(al[mt], H1, acc[mt][2*(P)+1], 0, 0, 0); \
        acc[mt][2*(P)+1] = __builtin_amdgcn_mfma_f32_16x16x32_f16(ah[mt], L1, acc[mt][2*(P)+1], 0, 0, 0); \
    } \
    __builtin_amdgcn_s_setprio(0); \
    __builtin_amdgcn_sched_barrier(0); \
} while (0)

    floatx4 acc[4][8];
    half8 ah[4], al[4];
    int cur = 0;

    // prologue stage: all 8 loads for step 0 (one-time burst)
    STAGE_A(0, 0, 0, 0); STAGE_A(0, 0, 0, 1);
    STAGE_A(0, 0, 1, 0); STAGE_A(0, 0, 1, 1);
    STAGE_B(0, 0, 0, 0); STAGE_B(0, 0, 0, 1);
    STAGE_B(0, 0, 0, 2); STAGE_B(0, 0, 0, 3);

#pragma unroll 1
    for (int t = 0; t < 128; ++t) {
        const int nxt = cur ^ 1;
        const int tn  = t + 1;
        const int vtn = tn >> 4;
        const int kon = (tn & 15) << 5;
        const int vt  = t >> 4;

        if ((t & 15) == 0) {
#pragma unroll
            for (int mt = 0; mt < 4; ++mt)
#pragma unroll
                for (int nt = 0; nt < 8; ++nt) acc[mt][nt] = (floatx4){0.f, 0.f, 0.f, 0.f};
        }

        // ---- step-top publication: buf[cur] fully visible after this barrier ----
        asm volatile("s_waitcnt vmcnt(0)" ::: "memory");
        __builtin_amdgcn_s_barrier();

        half8 s0h0, s0l0, s0h1, s0l1, s1h0, s1l0, s1h1, s1l1;

        // phase 0: A frags + B chunk0 reads (only exposed reads of the step)
#pragma unroll
        for (int mt = 0; mt < 4; ++mt) {
            const int aro = (wm * 64 + mt * 16 + cl) * 32 + brq;
            ah[mt] = *(const half8*)&AsH[cur][aro];
            al[mt] = *(const half8*)&AsL[cur][aro];
        }
        READ_B(0, s0h0, s0l0, s0h1, s0l1);
        if (t < 127) { STAGE_A(nxt, kon, 0, 0); STAGE_A(nxt, kon, 0, 1); }
        asm volatile("s_waitcnt lgkmcnt(0)" ::: "memory");
        __builtin_amdgcn_sched_barrier(0);
        MFMA_CHUNK(0, s0h0, s0l0, s0h1, s0l1);
        // pre-issue phase 1 reads + stage under barrier slack
        READ_B(1, s1h0, s1l0, s1h1, s1l1);
        if (t < 127) { STAGE_A(nxt, kon, 1, 0); STAGE_A(nxt, kon, 1, 1); }
        __builtin_amdgcn_sched_barrier(0);

        __builtin_amdgcn_s_barrier();          // phase 1 alignment
        asm volatile("s_waitcnt lgkmcnt(0)" ::: "memory");
        __builtin_amdgcn_sched_barrier(0);
        MFMA_CHUNK(1, s1h0, s1l0, s1h1, s1l1);
        READ_B(2, s0h0, s0l0, s0h1, s0l1);     // set0 free since chunk0 done
        if (t < 127) { STAGE_B(nxt, vtn, kon, 0); STAGE_B(nxt, vtn, kon, 1); }
        __builtin_amdgcn_sched_barrier(0);

        __builtin_amdgcn_s_barrier();          // phase 2 alignment
        asm volatile("s_waitcnt lgkmcnt(0)" ::: "memory");
        __builtin_amdgcn_sched_barrier(0);
        MFMA_CHUNK(2, s0h0, s0l0, s0h1, s0l1);
        READ_B(3, s1h0, s1l0, s1h1, s1l1);     // set1 free since chunk1 done
        if (t < 127) { STAGE_B(nxt, vtn, kon, 2); STAGE_B(nxt, vtn, kon, 3); }
        __builtin_amdgcn_sched_barrier(0);

        __builtin_amdgcn_s_barrier();          // phase 3 alignment
        asm volatile("s_waitcnt lgkmcnt(0)" ::: "memory");
        __builtin_amdgcn_sched_barrier(0);
        MFMA_CHUNK(3, s1h0, s1l0, s1h1, s1l1);
        cur = nxt;

        if ((t & 15) == 15) {
            // per-vt argmax epilogue (c2 from LDS; no VMEM here)
            float c2v[8];
#pragma unroll
            for (int nt = 0; nt < 8; ++nt)
                c2v[nt] = c2s[vt * 256 + wn * 128 + nt * 16 + cl];
#pragma unroll
            for (int mt = 0; mt < 4; ++mt)
#pragma unroll
                for (int r = 0; r < 4; ++r) {
                    float bv = acc[mt][0][r] - c2v[0];
                    int   bi = vt * 256 + wn * 128 + cl;
#pragma unroll
                    for (int nt = 1; nt < 8; ++nt) {
                        float m = acc[mt][nt][r] - c2v[nt];
                        int   vi = vt * 256 + wn * 128 + nt * 16 + cl;
                        if (m > bv) { bv = m; bi = vi; }
                    }
#pragma unroll
                    for (int msk = 1; msk < 16; msk <<= 1) {
                        float ov = __shfl_xor(bv, msk, 64);
                        int   oi = __shfl_xor(bi, msk, 64);
                        if (ov > bv || (ov == bv && oi < bi)) { bv = ov; bi = oi; }
                    }
                    if (cl == 0) {
                        const int row = wm * 64 + mt * 16 + q * 4 + r;
                        float cur_v = slotv[wn][row];
                        int   ci  = sloti[wn][row];
                        if (bv > cur_v || (bv == cur_v && bi < ci)) {
                            slotv[wn][row] = bv;
                            sloti[wn][row] = bi;
                        }
                    }
                }
        }
    }
#undef MFMA_CHUNK
#undef READ_B
#undef STAGE_A
#undef STAGE_B

    __syncthreads();
    if (tid < 256) {
        float v0 = slotv[0][tid], v1 = slotv[1][tid];
        int   i0 = sloti[0][tid], i1 = sloti[1][tid];
        bool t1 = (v1 > v0);  // wn=1 indices always larger: ties keep wn=0
        int best = t1 ? i1 : i0;
        const int n = (b * KCB + k) * L3V + l0 + tid;
        tok_i[n] = best;
        tok_f[n] = (float)best;
    }
}

// ---------------- embedding mean over 4 codebooks ----------------
__global__ void emb_kernel(const int* __restrict__ tokens, const float* __restrict__ E,
                           float* __restrict__ out) {
    const int l = blockIdx.x;
    const int b = blockIdx.y;
    const int h4 = threadIdx.x * 4;
    const int t0 = tokens[((size_t)(b * KCB + 0)) * L3V + l];
    const int t1 = tokens[((size_t)(b * KCB + 1)) * L3V + l];
    const int t2 = tokens[((size_t)(b * KCB + 2)) * L3V + l];
    const int t3 = tokens[((size_t)(b * KCB + 3)) * L3V + l];
    const float4 e0 = *(const float4*)&E[(size_t)t0 * 512 + h4];
    const float4 e1 = *(const float4*)&E[(size_t)t1 * 512 + h4];
    const float4 e2 = *(const float4*)&E[(size_t)t2 * 512 + h4];
    const float4 e3 = *(const float4*)&E[(size_t)t3 * 512 + h4];
    float4 r;
    r.x = (e0.x + e1.x + e2.x + e3.x) * 0.25f;
    r.y = (e0.y + e1.y + e2.y + e3.y) * 0.25f;
    r.z = (e0.z + e1.z + e2.z + e3.z) * 0.25f;
    r.w = (e0.w + e1.w + e2.w + e3.w) * 0.25f;
    *(float4*)&out[((size_t)b * L3V + l) * 512 + h4] = r;
}

extern "C" void kernel_launch(void* const* d_in, const int* in_sizes, int n_in,
                              void* d_out, int out_size, void* d_ws, size_t ws_size,
                              hipStream_t stream) {
    const float* audio = (const float*)d_in[0];
    const float* w1 = (const float*)d_in[1];
    const float* b1 = (const float*)d_in[2];
    const float* w2 = (const float*)d_in[3];
    const float* b2 = (const float*)d_in[4];
    const float* w3 = (const float*)d_in[5];
    const float* b3 = (const float*)d_in[6];
    const float* cb = (const float*)d_in[7];
    const float* E  = (const float*)d_in[8];

    float* out_tok = (float*)d_out;
    float* out_emb = out_tok + (size_t)B_ * KCB * L3V;

    float* ws = (float*)d_ws;
    size_t off = 0;
    // x1: hi/lo f16 planes, B*C1V rows x 2*(L1V+16) halfs; reused as Afh after conv2.
    float* x1f = ws + off; off += (size_t)B_ * C1V * (L1V + 16);
    // x2: hi/lo f16 planes for conv2 out; reused as Bfh after conv3 consumes x2.
    float* x2f = ws + off; off += (size_t)B_ * C2V * (L2V + 16);
    float* w2h_f = ws + off; off += (size_t)C2V * (C1V * 8) / 2;
    float* w2l_f = ws + off; off += (size_t)C2V * (C1V * 8) / 2;
    float* w3h_f = ws + off; off += (size_t)C3V * (C2V * 8) / 2;
    float* w3l_f = ws + off; off += (size_t)C3V * (C2V * 8) / 2;
    float* c2p = ws + off; off += (size_t)KCB * VOCABV;
    int*   tok = (int*)(ws + off); off += (size_t)B_ * KCB * L3V;

    _Float16* X1  = (_Float16*)x1f;
    _Float16* X2  = (_Float16*)x2f;
    _Float16* Afh = (_Float16*)x1f;   // conv3 writes over x1 (dead after conv2)
    _Float16* Bfh = (_Float16*)x2f;   // cbprep writes over x2 (dead after conv3)
    _Float16* W2H = (_Float16*)w2h_f; _Float16* W2L = (_Float16*)w2l_f;
    _Float16* W3H = (_Float16*)w3h_f; _Float16* W3L = (_Float16*)w3l_f;

    padzero_kernel<<<24, 256, 0, stream>>>(X1, X2);

    wsplit_kernel<<<(C2V * C1V + 255) / 256, 256, 0, stream>>>(w2, W2H, W2L, C1V, C2V);
    wsplit_kernel<<<(C3V * C2V + 255) / 256, 256, 0, stream>>>(w3, W3H, W3L, C2V, C3V);

    conv1_kernel<<<dim3(L1V / 256, C1V, B_), 256, 0, stream>>>(audio, w1, b1, X1);

    conv2_mfma_kernel<<<dim3(L2V / 128, C2V / 128, B_), 256, 0, stream>>>(
        X1, W2H, W2L, b2, X2);

    conv3_mfma_kernel<<<dim3(L3V / 128, C3V / 128, B_), 256, 0, stream>>>(
        X2, W3H, W3L, b3, Afh);

    cbprep_kernel<<<KCB * VOCABV, 64, 0, stream>>>(cb, Bfh, c2p);

    cross_mfma_kernel<<<dim3(L3V / 256, KCB, B_), 512, 0, stream>>>(
        Afh, Bfh, c2p, tok, out_tok);

    emb_kernel<<<dim3(L3V, B_), 128, 0, stream>>>(tok, E, out_emb);
}